// Round 6
// baseline (43.685 us; speedup 1.0000x reference)
//
#include <hip/hip_runtime.h>

#define DD 32
#define PP 32
#define HH 64
#define TPB 256
#define ROWS 128

// main LUT: 32 x 512 pairs over [M_LO, M_HI]
#define M_NE 512
#define M_LO (-8.0f)
#define M_HI (8.0f)
// inter LUT: 32 x 128 x 128 float4 cells over [I_LO, I_HI]^2
#define I_NE 128
#define I_LO (-6.5f)
#define I_HI (6.5f)

#define MAIN_BLOCKS ((DD * M_NE) / TPB)            // 64
#define INTER_BLOCKS ((PP * I_NE * I_NE) / TPB)    // 2048

__device__ __forceinline__ float silu_fast(float t) {
    const float LOG2E = 1.4426950408889634f;
    return t * __builtin_amdgcn_rcpf(1.f + __builtin_amdgcn_exp2f(-t * LOG2E));
}

// ---------------- fused LUT builder ----------------
// LUTm2[d][i] = (f(i), f(i+1)) as float2  -> one aligned 8B gather at lookup
// LUTi4[p][iu][iv] = (f(iu,iv), f(iu,iv+1), f(iu+1,iv), f(iu+1,iv+1)) float4
__global__ void build_luts(const float* __restrict__ lwm,
                           const float* __restrict__ vm,
                           const float* __restrict__ lwi,
                           const float* __restrict__ vi,
                           float2* __restrict__ LUTm2,
                           float4* __restrict__ LUTi4)
{
    const float LOG2E = 1.4426950408889634f;
    __shared__ float2 sew[HH];
    __shared__ float  sv[HH];

    if (blockIdx.x < MAIN_BLOCKS) {
        const float h = (M_HI - M_LO) / (float)(M_NE - 1);
        int idx = blockIdx.x * TPB + threadIdx.x;
        int d = idx >> 9;                 // /512 (uniform per block)
        int i = idx & (M_NE - 1);
        float s = M_LO + (float)i * h;
        float acc = 0.f;
        #pragma unroll 8
        for (int k = 0; k < HH; ++k) {
            float w = __builtin_amdgcn_exp2f(lwm[d * HH + k] * LOG2E);
            acc = fmaf(silu_fast(s * w), vm[d * HH + k], acc);
        }
        float* base = reinterpret_cast<float*>(LUTm2 + (d << 9));
        if (i < M_NE - 1) base[2 * i + 0] = acc;       // pair[i].x
        if (i > 0)        base[2 * (i - 1) + 1] = acc; // pair[i-1].y
    } else {
        const float h = (I_HI - I_LO) / (float)(I_NE - 1);
        int idx = (blockIdx.x - MAIN_BLOCKS) * TPB + threadIdx.x;
        int p = idx >> 14;                        // uniform per block
        int i = (idx >> 7) & (I_NE - 1);
        int j = idx & (I_NE - 1);
        if (threadIdx.x < HH) {
            int t = threadIdx.x;
            sew[t] = make_float2(
                __builtin_amdgcn_exp2f(lwi[(p * HH + t) * 2 + 0] * LOG2E),
                __builtin_amdgcn_exp2f(lwi[(p * HH + t) * 2 + 1] * LOG2E));
            sv[t] = vi[p * HH + t];
        }
        __syncthreads();
        float c0 = I_LO + (float)i * h;
        float c1 = I_LO + (float)j * h;
        float acc = 0.f;
        #pragma unroll 8
        for (int k = 0; k < HH; ++k) {
            float a = fmaf(c0, sew[k].x, c1 * sew[k].y);
            acc = fmaf(silu_fast(a), sv[k], acc);
        }
        float* cb = reinterpret_cast<float*>(LUTi4 + ((size_t)p << 14));
        if (i < I_NE - 1 && j < I_NE - 1) cb[((i    ) * I_NE + j    ) * 4 + 0] = acc;
        if (i < I_NE - 1 && j > 0)        cb[((i    ) * I_NE + j - 1) * 4 + 1] = acc;
        if (i > 0        && j < I_NE - 1) cb[((i - 1) * I_NE + j    ) * 4 + 2] = acc;
        if (i > 0        && j > 0)        cb[((i - 1) * I_NE + j - 1) * 4 + 3] = acc;
    }
}

// ---------------- main kernel: 2 threads per row ----------------
__global__ __launch_bounds__(TPB, 4) void qgam_main(
    const float* __restrict__ X,
    const float* __restrict__ bias_main,
    const float* __restrict__ bias_inter,
    const float* __restrict__ W_final,
    const float* __restrict__ b_final,
    const int* __restrict__ pairs,
    const float2* __restrict__ LUTm2,
    const float4* __restrict__ LUTi4,
    float* __restrict__ out,
    float* __restrict__ Zout,
    int nrows)
{
    const float M_INVH = (float)(M_NE - 1) / (M_HI - M_LO);
    const float M_OFF  = -M_LO * M_INVH;
    const float I_INVH = (float)(I_NE - 1) / (I_HI - I_LO);
    const float I_OFF  = -I_LO * I_INVH;

    __shared__ float s_x[DD][ROWS + 1];   // 16.5 KB, X transposed
    __shared__ float s_t[DD][ROWS + 1];   // 16.5 KB, Z staging (one 32-col round)
    __shared__ float s_dot[ROWS];
    __shared__ float s_wf[DD + PP];
    __shared__ float s_bm[DD];
    __shared__ float s_bi0[PP], s_bi1[PP];
    __shared__ int   s_p0[PP], s_p1[PP];

    const int tid  = threadIdx.x;
    const int base = blockIdx.x * ROWS;

    // ---- stage X tile coalesced -> LDS transposed (128 rows x 32 cols) ----
    {
        const float4* __restrict__ Xv =
            reinterpret_cast<const float4*>(X) + (size_t)base * (DD / 4);
        #pragma unroll
        for (int k = 0; k < 4; ++k) {
            const int fi = k * TPB + tid;           // 0..1023 float4 units
            const int rl = fi >> 3;                 // local row
            const int c  = (fi & 7) * 4;            // starting col
            if (base + rl < nrows) {
                float4 v = Xv[fi];
                s_x[c + 0][rl] = v.x;
                s_x[c + 1][rl] = v.y;
                s_x[c + 2][rl] = v.z;
                s_x[c + 3][rl] = v.w;
            }
        }
    }
    if (tid < DD + PP) s_wf[tid] = W_final[tid];
    if (tid < PP) {
        s_bm[tid]  = bias_main[tid];
        s_bi0[tid] = bias_inter[2 * tid + 0];
        s_bi1[tid] = bias_inter[2 * tid + 1];
        s_p0[tid]  = pairs[2 * tid + 0];
        s_p1[tid]  = pairs[2 * tid + 1];
    }
    __syncthreads();

    const int r  = tid & (ROWS - 1);     // local row
    const int hf = tid >> 7;             // column half: 0 or 1
    const int cb = hf * 16;              // this thread's 16-col base
    const int n  = base + r;

    float dot = (hf == 0) ? b_final[0] : 0.f;

    // ---- main part: 16 lerps from packed float2 LUT ----
    #pragma unroll
    for (int k = 0; k < 16; ++k) {
        const int d = cb + k;
        const float s = s_x[d][r] - s_bm[d];
        float u  = fmaf(s, M_INVH, M_OFF);
        int   ii = (int)floorf(u);
        ii = ii < 0 ? 0 : (ii > M_NE - 2 ? M_NE - 2 : ii);
        float f  = u - (float)ii;
        float2 t = LUTm2[(d << 9) + ii];
        float zv = fmaf(f, t.y - t.x, t.x);
        s_t[d][r] = zv;
        dot = fmaf(zv, s_wf[d], dot);
    }

    // flush round 0: Z cols 0..31 (full 128B line per 8 lanes)
    __syncthreads();
    #pragma unroll
    for (int i = 0; i < 4; ++i) {
        const int fi   = i * TPB + tid;
        const int rowl = fi >> 3;
        const int c4   = (fi & 7) * 4;
        const int row  = base + rowl;
        if (row < nrows) {
            float4 v = make_float4(s_t[c4 + 0][rowl], s_t[c4 + 1][rowl],
                                   s_t[c4 + 2][rowl], s_t[c4 + 3][rowl]);
            *reinterpret_cast<float4*>(&Zout[(size_t)row * (DD + PP) + c4]) = v;
        }
    }
    __syncthreads();

    // ---- inter part: 16 bilerps from float4 cell LUT ----
    #pragma unroll
    for (int k = 0; k < 16; ++k) {
        const int p = cb + k;
        const int i0 = s_p0[p], i1 = s_p1[p];
        const float c0 = s_x[i0][r] - s_bi0[p];
        const float c1 = s_x[i1][r] - s_bi1[p];
        float u  = fmaf(c0, I_INVH, I_OFF);
        float v_ = fmaf(c1, I_INVH, I_OFF);
        int   iu = (int)floorf(u);
        int   iv = (int)floorf(v_);
        iu = iu < 0 ? 0 : (iu > I_NE - 2 ? I_NE - 2 : iu);
        iv = iv < 0 ? 0 : (iv > I_NE - 2 ? I_NE - 2 : iv);
        float fu = u  - (float)iu;
        float fv = v_ - (float)iv;
        float4 cell = LUTi4[((size_t)p << 14) + (iu << 7) + iv];
        float r0 = fmaf(fv, cell.y - cell.x, cell.x);
        float r1 = fmaf(fv, cell.w - cell.z, cell.z);
        float zv = fmaf(fu, r1 - r0, r0);
        s_t[p][r] = zv;                  // staging col p -> Z col 32+p
        dot = fmaf(zv, s_wf[DD + p], dot);
    }
    if (hf == 1) s_dot[r] = dot;

    __syncthreads();
    if (hf == 0 && n < nrows) out[n] = dot + s_dot[r];

    // flush round 1: Z cols 32..63
    #pragma unroll
    for (int i = 0; i < 4; ++i) {
        const int fi   = i * TPB + tid;
        const int rowl = fi >> 3;
        const int c4   = (fi & 7) * 4;
        const int row  = base + rowl;
        if (row < nrows) {
            float4 v = make_float4(s_t[c4 + 0][rowl], s_t[c4 + 1][rowl],
                                   s_t[c4 + 2][rowl], s_t[c4 + 3][rowl]);
            *reinterpret_cast<float4*>(&Zout[(size_t)row * (DD + PP) + DD + c4]) = v;
        }
    }
}

extern "C" void kernel_launch(void* const* d_in, const int* in_sizes, int n_in,
                              void* d_out, int out_size, void* d_ws, size_t ws_size,
                              hipStream_t stream) {
    const float* X   = (const float*)d_in[0];
    const float* lwm = (const float*)d_in[1];
    const float* bm  = (const float*)d_in[2];
    const float* vm  = (const float*)d_in[3];
    const float* lwi = (const float*)d_in[4];
    const float* bi  = (const float*)d_in[5];
    const float* vi  = (const float*)d_in[6];
    const float* wf  = (const float*)d_in[7];
    const float* bf  = (const float*)d_in[8];
    const int* pairs = (const int*)d_in[9];

    const int nrows = in_sizes[0] / DD;
    float* out = (float*)d_out;          // (N,)
    float* Z   = out + nrows;            // (N, 64)

    float2* LUTm2 = (float2*)d_ws;                       // 32*512*8B  = 128 KB
    float4* LUTi4 = (float4*)((char*)d_ws + DD * M_NE * sizeof(float2));
                                                         // 32*128*128*16B = 8 MB

    build_luts<<<MAIN_BLOCKS + INTER_BLOCKS, TPB, 0, stream>>>(lwm, vm, lwi, vi,
                                                               LUTm2, LUTi4);

    const int grid = (nrows + ROWS - 1) / ROWS;
    qgam_main<<<grid, TPB, 0, stream>>>(X, bm, bi, wf, bf, pairs, LUTm2, LUTi4,
                                        out, Z, nrows);
}

// Round 7
// 43.225 us; speedup vs baseline: 1.0106x; 1.0106x over previous
//
#include <hip/hip_runtime.h>

#define DD 32
#define PP 32
#define HH 64
#define TPB 256
#define ROWS 128

// main LUT: 32 x 256 scalars over [M_LO, M_HI] (lives in LDS during main kernel)
#define M_NE 256
#define M_LO (-8.0f)
#define M_HI (8.0f)
// inter LUT: 32 x 128 x 128 float4 cells over [I_LO, I_HI]^2
#define I_NE 128
#define I_LO (-6.5f)
#define I_HI (6.5f)

#define MAIN_BLOCKS ((DD * M_NE) / TPB)            // 32 (one d per block)
#define INTER_BLOCKS ((PP * I_NE * I_NE) / TPB)    // 2048

__device__ __forceinline__ float silu_fast(float t) {
    const float LOG2E = 1.4426950408889634f;
    return t * __builtin_amdgcn_rcpf(1.f + __builtin_amdgcn_exp2f(-t * LOG2E));
}

// ---------------- fused LUT builder ----------------
__global__ void build_luts(const float* __restrict__ lwm,
                           const float* __restrict__ vm,
                           const float* __restrict__ lwi,
                           const float* __restrict__ vi,
                           float* __restrict__ LUTm,
                           float4* __restrict__ LUTi4)
{
    const float LOG2E = 1.4426950408889634f;
    __shared__ float2 sew[HH];
    __shared__ float  sv[HH];

    if (blockIdx.x < MAIN_BLOCKS) {
        // one d per block: stage its 64 weights
        const int d = blockIdx.x;
        if (threadIdx.x < HH) {
            int t = threadIdx.x;
            sew[t] = make_float2(
                __builtin_amdgcn_exp2f(lwm[d * HH + t] * LOG2E), 0.f);
            sv[t] = vm[d * HH + t];
        }
        __syncthreads();
        const float h = (M_HI - M_LO) / (float)(M_NE - 1);
        int i = threadIdx.x;                     // 0..255
        float s = M_LO + (float)i * h;
        float acc = 0.f;
        #pragma unroll 8
        for (int k = 0; k < HH; ++k)
            acc = fmaf(silu_fast(s * sew[k].x), sv[k], acc);
        LUTm[d * M_NE + i] = acc;
    } else {
        const float h = (I_HI - I_LO) / (float)(I_NE - 1);
        int idx = (blockIdx.x - MAIN_BLOCKS) * TPB + threadIdx.x;
        int p = idx >> 14;                        // uniform per block
        int i = (idx >> 7) & (I_NE - 1);
        int j = idx & (I_NE - 1);
        if (threadIdx.x < HH) {
            int t = threadIdx.x;
            sew[t] = make_float2(
                __builtin_amdgcn_exp2f(lwi[(p * HH + t) * 2 + 0] * LOG2E),
                __builtin_amdgcn_exp2f(lwi[(p * HH + t) * 2 + 1] * LOG2E));
            sv[t] = vi[p * HH + t];
        }
        __syncthreads();
        float c0 = I_LO + (float)i * h;
        float c1 = I_LO + (float)j * h;
        float acc = 0.f;
        #pragma unroll 8
        for (int k = 0; k < HH; ++k) {
            float a = fmaf(c0, sew[k].x, c1 * sew[k].y);
            acc = fmaf(silu_fast(a), sv[k], acc);
        }
        float* cb = reinterpret_cast<float*>(LUTi4 + ((size_t)p << 14));
        if (i < I_NE - 1 && j < I_NE - 1) cb[((i    ) * I_NE + j    ) * 4 + 0] = acc;
        if (i < I_NE - 1 && j > 0)        cb[((i    ) * I_NE + j - 1) * 4 + 1] = acc;
        if (i > 0        && j < I_NE - 1) cb[((i - 1) * I_NE + j    ) * 4 + 2] = acc;
        if (i > 0        && j > 0)        cb[((i - 1) * I_NE + j - 1) * 4 + 3] = acc;
    }
}

// ---------------- main kernel: 2 threads/row, LDS main-LUT, batched gathers ----
__global__ __launch_bounds__(TPB, 2) void qgam_main(
    const float* __restrict__ X,
    const float* __restrict__ bias_main,
    const float* __restrict__ bias_inter,
    const float* __restrict__ W_final,
    const float* __restrict__ b_final,
    const int* __restrict__ pairs,
    const float* __restrict__ LUTm,
    const float4* __restrict__ LUTi4,
    float* __restrict__ out,
    float* __restrict__ Zout,
    int nrows)
{
    const float M_INVH = (float)(M_NE - 1) / (M_HI - M_LO);
    const float I_INVH = (float)(I_NE - 1) / (I_HI - I_LO);

    __shared__ float s_lutm[DD * M_NE];   // 32 KB
    __shared__ float s_x[DD][ROWS + 1];   // 16.5 KB
    __shared__ float s_t[DD][ROWS + 1];   // 16.5 KB
    __shared__ float s_dot[ROWS];
    __shared__ float s_wf[DD + PP];
    __shared__ float s_moff[DD];          // -(bm[d]+M_LO)*M_INVH
    __shared__ float s_io0[PP], s_io1[PP];
    __shared__ int   s_p0[PP], s_p1[PP];

    const int tid  = threadIdx.x;
    const int base = blockIdx.x * ROWS;

    // copy main LUT -> LDS (coalesced, L2-resident)
    {
        const float4* __restrict__ lm4 = reinterpret_cast<const float4*>(LUTm);
        float4* __restrict__ sl4 = reinterpret_cast<float4*>(s_lutm);
        #pragma unroll
        for (int k = 0; k < 8; ++k) {
            const int fi = k * TPB + tid;        // 0..2047
            sl4[fi] = lm4[fi];
        }
    }
    // stage X tile coalesced -> LDS transposed
    {
        const float4* __restrict__ Xv =
            reinterpret_cast<const float4*>(X) + (size_t)base * (DD / 4);
        #pragma unroll
        for (int k = 0; k < 4; ++k) {
            const int fi = k * TPB + tid;
            const int rl = fi >> 3;
            const int c  = (fi & 7) * 4;
            if (base + rl < nrows) {
                float4 v = Xv[fi];
                s_x[c + 0][rl] = v.x;
                s_x[c + 1][rl] = v.y;
                s_x[c + 2][rl] = v.z;
                s_x[c + 3][rl] = v.w;
            }
        }
    }
    if (tid < DD + PP) s_wf[tid] = W_final[tid];
    if (tid < PP) {
        s_moff[tid] = -(bias_main[tid] + M_LO) * M_INVH;
        s_io0[tid]  = -(bias_inter[2 * tid + 0] + I_LO) * I_INVH;
        s_io1[tid]  = -(bias_inter[2 * tid + 1] + I_LO) * I_INVH;
        s_p0[tid]   = pairs[2 * tid + 0];
        s_p1[tid]   = pairs[2 * tid + 1];
    }
    __syncthreads();

    const int r  = tid & (ROWS - 1);     // local row
    const int hf = tid >> 7;             // column half: 0 or 1
    const int cb = hf * 16;
    const int n  = base + r;

    float dot = (hf == 0) ? b_final[0] : 0.f;

    // ---- main part: 16 LDS lerps ----
    #pragma unroll
    for (int k = 0; k < 16; ++k) {
        const int d = cb + k;
        float u  = fmaf(s_x[d][r], M_INVH, s_moff[d]);
        int   ii = (int)floorf(u);
        ii = ii < 0 ? 0 : (ii > M_NE - 2 ? M_NE - 2 : ii);
        float f  = u - (float)ii;
        float t0 = s_lutm[(d << 8) + ii];
        float t1 = s_lutm[(d << 8) + ii + 1];
        float zv = fmaf(f, t1 - t0, t0);
        s_t[d][r] = zv;
        dot = fmaf(zv, s_wf[d], dot);
    }

    // flush round 0: Z cols 0..31
    __syncthreads();
    #pragma unroll
    for (int i = 0; i < 4; ++i) {
        const int fi   = i * TPB + tid;
        const int rowl = fi >> 3;
        const int c4   = (fi & 7) * 4;
        const int row  = base + rowl;
        if (row < nrows) {
            float4 v = make_float4(s_t[c4 + 0][rowl], s_t[c4 + 1][rowl],
                                   s_t[c4 + 2][rowl], s_t[c4 + 3][rowl]);
            *reinterpret_cast<float4*>(&Zout[(size_t)row * (DD + PP) + c4]) = v;
        }
    }
    __syncthreads();

    // ---- inter part: phase A issues all 16 gathers, phase B consumes ----
    float4 cell[16];
    float  fu[16], fv[16];
    #pragma unroll
    for (int k = 0; k < 16; ++k) {
        const int p = cb + k;
        float u  = fmaf(s_x[s_p0[p]][r], I_INVH, s_io0[p]);
        float v_ = fmaf(s_x[s_p1[p]][r], I_INVH, s_io1[p]);
        int   iu = (int)floorf(u);
        int   iv = (int)floorf(v_);
        iu = iu < 0 ? 0 : (iu > I_NE - 2 ? I_NE - 2 : iu);
        iv = iv < 0 ? 0 : (iv > I_NE - 2 ? I_NE - 2 : iv);
        fu[k] = u  - (float)iu;
        fv[k] = v_ - (float)iv;
        cell[k] = LUTi4[((size_t)p << 14) + (iu << 7) + iv];
    }
    #pragma unroll
    for (int k = 0; k < 16; ++k) {
        const int p = cb + k;
        float r0 = fmaf(fv[k], cell[k].y - cell[k].x, cell[k].x);
        float r1 = fmaf(fv[k], cell[k].w - cell[k].z, cell[k].z);
        float zv = fmaf(fu[k], r1 - r0, r0);
        s_t[p][r] = zv;
        dot = fmaf(zv, s_wf[DD + p], dot);
    }
    if (hf == 1) s_dot[r] = dot;

    __syncthreads();
    if (hf == 0 && n < nrows) out[n] = dot + s_dot[r];

    // flush round 1: Z cols 32..63
    #pragma unroll
    for (int i = 0; i < 4; ++i) {
        const int fi   = i * TPB + tid;
        const int rowl = fi >> 3;
        const int c4   = (fi & 7) * 4;
        const int row  = base + rowl;
        if (row < nrows) {
            float4 v = make_float4(s_t[c4 + 0][rowl], s_t[c4 + 1][rowl],
                                   s_t[c4 + 2][rowl], s_t[c4 + 3][rowl]);
            *reinterpret_cast<float4*>(&Zout[(size_t)row * (DD + PP) + DD + c4]) = v;
        }
    }
}

extern "C" void kernel_launch(void* const* d_in, const int* in_sizes, int n_in,
                              void* d_out, int out_size, void* d_ws, size_t ws_size,
                              hipStream_t stream) {
    const float* X   = (const float*)d_in[0];
    const float* lwm = (const float*)d_in[1];
    const float* bm  = (const float*)d_in[2];
    const float* vm  = (const float*)d_in[3];
    const float* lwi = (const float*)d_in[4];
    const float* bi  = (const float*)d_in[5];
    const float* vi  = (const float*)d_in[6];
    const float* wf  = (const float*)d_in[7];
    const float* bf  = (const float*)d_in[8];
    const int* pairs = (const int*)d_in[9];

    const int nrows = in_sizes[0] / DD;
    float* out = (float*)d_out;          // (N,)
    float* Z   = out + nrows;            // (N, 64)

    float*  LUTm  = (float*)d_ws;                        // 32*256*4B = 32 KB
    float4* LUTi4 = (float4*)((char*)d_ws + ((DD * M_NE * sizeof(float) + 255) & ~255));
                                                         // 32*128*128*16B = 8 MB

    build_luts<<<MAIN_BLOCKS + INTER_BLOCKS, TPB, 0, stream>>>(lwm, vm, lwi, vi,
                                                               LUTm, LUTi4);

    const int grid = (nrows + ROWS - 1) / ROWS;
    qgam_main<<<grid, TPB, 0, stream>>>(X, bm, bi, wf, bf, pairs, LUTm, LUTi4,
                                        out, Z, nrows);
}

// Round 8
// 34.222 us; speedup vs baseline: 1.2765x; 1.2631x over previous
//
#include <hip/hip_runtime.h>

#define DD 32
#define PP 32
#define HH 64
#define TPB 256
#define ROWS 128

// main LUT: 32 x 256 scalars over [M_LO, M_HI] (lives in LDS during main kernel)
#define M_NE 256
#define M_LO (-8.0f)
#define M_HI (8.0f)
// inter LUT: 32 x 96 x 96 bf16x4 cells over [I_LO, I_HI]^2
#define I_NE 96
#define I_LO (-6.5f)
#define I_HI (6.5f)
#define I_CELLS (I_NE * I_NE)                      // 9216
#define BLOCKS_PER_P (I_CELLS / TPB)               // 36

#define MAIN_BLOCKS 32                             // one d per block (M_NE==TPB)
#define INTER_BLOCKS (PP * BLOCKS_PER_P)           // 1152

__device__ __forceinline__ float silu_fast(float t) {
    const float LOG2E = 1.4426950408889634f;
    return t * __builtin_amdgcn_rcpf(1.f + __builtin_amdgcn_exp2f(-t * LOG2E));
}

__device__ __forceinline__ unsigned short f2bf(float f) {
    unsigned u = __float_as_uint(f);
    u += 0x7FFF + ((u >> 16) & 1);          // round-to-nearest-even
    return (unsigned short)(u >> 16);
}

__device__ __forceinline__ float bf2f(unsigned short s) {
    return __uint_as_float((unsigned)s << 16);
}

// ---------------- fused LUT builder ----------------
__global__ void build_luts(const float* __restrict__ lwm,
                           const float* __restrict__ vm,
                           const float* __restrict__ lwi,
                           const float* __restrict__ vi,
                           float* __restrict__ LUTm,
                           unsigned short* __restrict__ LUTi)   // [32][96][96][4] bf16
{
    const float LOG2E = 1.4426950408889634f;
    __shared__ float2 sew[HH];
    __shared__ float  sv[HH];

    if (blockIdx.x < MAIN_BLOCKS) {
        const int d = blockIdx.x;
        if (threadIdx.x < HH) {
            int t = threadIdx.x;
            sew[t] = make_float2(
                __builtin_amdgcn_exp2f(lwm[d * HH + t] * LOG2E), 0.f);
            sv[t] = vm[d * HH + t];
        }
        __syncthreads();
        const float h = (M_HI - M_LO) / (float)(M_NE - 1);
        int i = threadIdx.x;                     // 0..255
        float s = M_LO + (float)i * h;
        float acc = 0.f;
        #pragma unroll 8
        for (int k = 0; k < HH; ++k)
            acc = fmaf(silu_fast(s * sew[k].x), sv[k], acc);
        LUTm[d * M_NE + i] = acc;
    } else {
        const float h = (I_HI - I_LO) / (float)(I_NE - 1);
        const int rel = blockIdx.x - MAIN_BLOCKS;
        const int p   = rel / BLOCKS_PER_P;        // uniform per block
        const int cip = (rel % BLOCKS_PER_P) * TPB + threadIdx.x;  // 0..9215
        const int i   = cip / I_NE;
        const int j   = cip - i * I_NE;
        if (threadIdx.x < HH) {
            int t = threadIdx.x;
            sew[t] = make_float2(
                __builtin_amdgcn_exp2f(lwi[(p * HH + t) * 2 + 0] * LOG2E),
                __builtin_amdgcn_exp2f(lwi[(p * HH + t) * 2 + 1] * LOG2E));
            sv[t] = vi[p * HH + t];
        }
        __syncthreads();
        float c0 = I_LO + (float)i * h;
        float c1 = I_LO + (float)j * h;
        float acc = 0.f;
        #pragma unroll 8
        for (int k = 0; k < HH; ++k) {
            float a = fmaf(c0, sew[k].x, c1 * sew[k].y);
            acc = fmaf(silu_fast(a), sv[k], acc);
        }
        unsigned short ab = f2bf(acc);
        unsigned short* cb = LUTi + (size_t)p * I_CELLS * 4;
        // scatter corner value into the <=4 cells that reference it
        if (i < I_NE - 1 && j < I_NE - 1) cb[((i    ) * I_NE + j    ) * 4 + 0] = ab;
        if (i < I_NE - 1 && j > 0)        cb[((i    ) * I_NE + j - 1) * 4 + 1] = ab;
        if (i > 0        && j < I_NE - 1) cb[((i - 1) * I_NE + j    ) * 4 + 2] = ab;
        if (i > 0        && j > 0)        cb[((i - 1) * I_NE + j - 1) * 4 + 3] = ab;
    }
}

// ---------------- main kernel: 2 threads/row, LDS main-LUT, bf16 cell gathers ----
__global__ __launch_bounds__(TPB, 2) void qgam_main(
    const float* __restrict__ X,
    const float* __restrict__ bias_main,
    const float* __restrict__ bias_inter,
    const float* __restrict__ W_final,
    const float* __restrict__ b_final,
    const int* __restrict__ pairs,
    const float* __restrict__ LUTm,
    const ushort4* __restrict__ LUTi,
    float* __restrict__ out,
    float* __restrict__ Zout,
    int nrows)
{
    const float M_INVH = (float)(M_NE - 1) / (M_HI - M_LO);
    const float I_INVH = (float)(I_NE - 1) / (I_HI - I_LO);

    __shared__ float s_lutm[DD * M_NE];   // 32 KB
    __shared__ float s_x[DD][ROWS + 1];   // 16.5 KB
    __shared__ float s_t[DD][ROWS + 1];   // 16.5 KB
    __shared__ float s_dot[ROWS];
    __shared__ float s_wf[DD + PP];
    __shared__ float s_moff[DD];          // -(bm[d]+M_LO)*M_INVH
    __shared__ float s_io0[PP], s_io1[PP];
    __shared__ int   s_p0[PP], s_p1[PP];

    const int tid  = threadIdx.x;
    const int base = blockIdx.x * ROWS;

    // copy main LUT -> LDS (coalesced, L2-resident)
    {
        const float4* __restrict__ lm4 = reinterpret_cast<const float4*>(LUTm);
        float4* __restrict__ sl4 = reinterpret_cast<float4*>(s_lutm);
        #pragma unroll
        for (int k = 0; k < 8; ++k) {
            const int fi = k * TPB + tid;        // 0..2047
            sl4[fi] = lm4[fi];
        }
    }
    // stage X tile coalesced -> LDS transposed
    {
        const float4* __restrict__ Xv =
            reinterpret_cast<const float4*>(X) + (size_t)base * (DD / 4);
        #pragma unroll
        for (int k = 0; k < 4; ++k) {
            const int fi = k * TPB + tid;
            const int rl = fi >> 3;
            const int c  = (fi & 7) * 4;
            if (base + rl < nrows) {
                float4 v = Xv[fi];
                s_x[c + 0][rl] = v.x;
                s_x[c + 1][rl] = v.y;
                s_x[c + 2][rl] = v.z;
                s_x[c + 3][rl] = v.w;
            }
        }
    }
    if (tid < DD + PP) s_wf[tid] = W_final[tid];
    if (tid < PP) {
        s_moff[tid] = -(bias_main[tid] + M_LO) * M_INVH;
        s_io0[tid]  = -(bias_inter[2 * tid + 0] + I_LO) * I_INVH;
        s_io1[tid]  = -(bias_inter[2 * tid + 1] + I_LO) * I_INVH;
        s_p0[tid]   = pairs[2 * tid + 0];
        s_p1[tid]   = pairs[2 * tid + 1];
    }
    __syncthreads();

    const int r  = tid & (ROWS - 1);     // local row
    const int hf = tid >> 7;             // column half: 0 or 1
    const int cb = hf * 16;
    const int n  = base + r;

    float dot = (hf == 0) ? b_final[0] : 0.f;

    // ---- main part: 16 LDS lerps ----
    #pragma unroll
    for (int k = 0; k < 16; ++k) {
        const int d = cb + k;
        float u  = fmaf(s_x[d][r], M_INVH, s_moff[d]);
        int   ii = (int)floorf(u);
        ii = ii < 0 ? 0 : (ii > M_NE - 2 ? M_NE - 2 : ii);
        float f  = u - (float)ii;
        float t0 = s_lutm[(d << 8) + ii];
        float t1 = s_lutm[(d << 8) + ii + 1];
        float zv = fmaf(f, t1 - t0, t0);
        s_t[d][r] = zv;
        dot = fmaf(zv, s_wf[d], dot);
    }

    // flush round 0: Z cols 0..31
    __syncthreads();
    #pragma unroll
    for (int i = 0; i < 4; ++i) {
        const int fi   = i * TPB + tid;
        const int rowl = fi >> 3;
        const int c4   = (fi & 7) * 4;
        const int row  = base + rowl;
        if (row < nrows) {
            float4 v = make_float4(s_t[c4 + 0][rowl], s_t[c4 + 1][rowl],
                                   s_t[c4 + 2][rowl], s_t[c4 + 3][rowl]);
            *reinterpret_cast<float4*>(&Zout[(size_t)row * (DD + PP) + c4]) = v;
        }
    }
    __syncthreads();

    // ---- inter part: phase A issues all 16 bf16-cell gathers, phase B consumes ----
    ushort4 cell[16];
    float   fu[16], fv[16];
    #pragma unroll
    for (int k = 0; k < 16; ++k) {
        const int p = cb + k;
        float u  = fmaf(s_x[s_p0[p]][r], I_INVH, s_io0[p]);
        float v_ = fmaf(s_x[s_p1[p]][r], I_INVH, s_io1[p]);
        int   iu = (int)floorf(u);
        int   iv = (int)floorf(v_);
        iu = iu < 0 ? 0 : (iu > I_NE - 2 ? I_NE - 2 : iu);
        iv = iv < 0 ? 0 : (iv > I_NE - 2 ? I_NE - 2 : iv);
        fu[k] = u  - (float)iu;
        fv[k] = v_ - (float)iv;
        cell[k] = LUTi[(size_t)p * I_CELLS + iu * I_NE + iv];
    }
    #pragma unroll
    for (int k = 0; k < 16; ++k) {
        const int p = cb + k;
        float a00 = bf2f(cell[k].x), a01 = bf2f(cell[k].y);
        float a10 = bf2f(cell[k].z), a11 = bf2f(cell[k].w);
        float r0 = fmaf(fv[k], a01 - a00, a00);
        float r1 = fmaf(fv[k], a11 - a10, a10);
        float zv = fmaf(fu[k], r1 - r0, r0);
        s_t[p][r] = zv;
        dot = fmaf(zv, s_wf[DD + p], dot);
    }
    if (hf == 1) s_dot[r] = dot;

    __syncthreads();
    if (hf == 0 && n < nrows) out[n] = dot + s_dot[r];

    // flush round 1: Z cols 32..63
    #pragma unroll
    for (int i = 0; i < 4; ++i) {
        const int fi   = i * TPB + tid;
        const int rowl = fi >> 3;
        const int c4   = (fi & 7) * 4;
        const int row  = base + rowl;
        if (row < nrows) {
            float4 v = make_float4(s_t[c4 + 0][rowl], s_t[c4 + 1][rowl],
                                   s_t[c4 + 2][rowl], s_t[c4 + 3][rowl]);
            *reinterpret_cast<float4*>(&Zout[(size_t)row * (DD + PP) + DD + c4]) = v;
        }
    }
}

extern "C" void kernel_launch(void* const* d_in, const int* in_sizes, int n_in,
                              void* d_out, int out_size, void* d_ws, size_t ws_size,
                              hipStream_t stream) {
    const float* X   = (const float*)d_in[0];
    const float* lwm = (const float*)d_in[1];
    const float* bm  = (const float*)d_in[2];
    const float* vm  = (const float*)d_in[3];
    const float* lwi = (const float*)d_in[4];
    const float* bi  = (const float*)d_in[5];
    const float* vi  = (const float*)d_in[6];
    const float* wf  = (const float*)d_in[7];
    const float* bf  = (const float*)d_in[8];
    const int* pairs = (const int*)d_in[9];

    const int nrows = in_sizes[0] / DD;
    float* out = (float*)d_out;          // (N,)
    float* Z   = out + nrows;            // (N, 64)

    float*          LUTm = (float*)d_ws;                 // 32*256*4B = 32 KB
    unsigned short* LUTi = (unsigned short*)((char*)d_ws +
                           ((DD * M_NE * sizeof(float) + 255) & ~255));
                           // 32*9216 cells * 8B = 2.36 MB

    build_luts<<<MAIN_BLOCKS + INTER_BLOCKS, TPB, 0, stream>>>(lwm, vm, lwi, vi,
                                                               LUTm, LUTi);

    const int grid = (nrows + ROWS - 1) / ROWS;
    qgam_main<<<grid, TPB, 0, stream>>>(X, bm, bi, wf, bf, pairs, LUTm,
                                        (const ushort4*)LUTi, out, Z, nrows);
}

// Round 9
// 33.663 us; speedup vs baseline: 1.2977x; 1.0166x over previous
//
#include <hip/hip_runtime.h>

#define DD 32
#define PP 32
#define HH 64
#define TPB 512
#define ROWS 512

// main LUT: 32 x 128 scalars over [M_LO, M_HI] (lives in LDS during main kernel)
#define M_NE 128
#define M_LO (-8.0f)
#define M_HI (8.0f)
// inter LUT: 32 x 96 x 96 bf16x4 cells over [I_LO, I_HI]^2
#define I_NE 96
#define I_LO (-6.5f)
#define I_HI (6.5f)
#define I_CELLS (I_NE * I_NE)                      // 9216

#define BTPB 256
#define MAIN_BLOCKS ((DD * M_NE) / BTPB)           // 16
#define BLOCKS_PER_P (I_CELLS / BTPB)              // 36
#define INTER_BLOCKS (PP * BLOCKS_PER_P)           // 1152

__device__ __forceinline__ float silu_fast(float t) {
    const float LOG2E = 1.4426950408889634f;
    return t * __builtin_amdgcn_rcpf(1.f + __builtin_amdgcn_exp2f(-t * LOG2E));
}

__device__ __forceinline__ unsigned short f2bf(float f) {
    unsigned u = __float_as_uint(f);
    u += 0x7FFF + ((u >> 16) & 1);          // round-to-nearest-even
    return (unsigned short)(u >> 16);
}

__device__ __forceinline__ float bf2f(unsigned short s) {
    return __uint_as_float((unsigned)s << 16);
}

// ---------------- fused LUT builder ----------------
__global__ void build_luts(const float* __restrict__ lwm,
                           const float* __restrict__ vm,
                           const float* __restrict__ lwi,
                           const float* __restrict__ vi,
                           float* __restrict__ LUTm,
                           unsigned short* __restrict__ LUTi)   // [32][96][96][4] bf16
{
    const float LOG2E = 1.4426950408889634f;
    __shared__ float2 sew[HH];
    __shared__ float  sv[HH];

    if (blockIdx.x < MAIN_BLOCKS) {
        const float h = (M_HI - M_LO) / (float)(M_NE - 1);
        int idx = blockIdx.x * BTPB + threadIdx.x;
        int d = idx >> 7;                 // 2 d's per block
        int i = idx & (M_NE - 1);
        float s = M_LO + (float)i * h;
        float acc = 0.f;
        #pragma unroll 8
        for (int k = 0; k < HH; ++k) {
            float w = __builtin_amdgcn_exp2f(lwm[d * HH + k] * LOG2E);
            acc = fmaf(silu_fast(s * w), vm[d * HH + k], acc);
        }
        LUTm[idx] = acc;
    } else {
        const float h = (I_HI - I_LO) / (float)(I_NE - 1);
        const int rel = blockIdx.x - MAIN_BLOCKS;
        const int p   = rel / BLOCKS_PER_P;        // uniform per block
        const int cip = (rel % BLOCKS_PER_P) * BTPB + threadIdx.x;  // 0..9215
        const int i   = cip / I_NE;
        const int j   = cip - i * I_NE;
        if (threadIdx.x < HH) {
            int t = threadIdx.x;
            sew[t] = make_float2(
                __builtin_amdgcn_exp2f(lwi[(p * HH + t) * 2 + 0] * LOG2E),
                __builtin_amdgcn_exp2f(lwi[(p * HH + t) * 2 + 1] * LOG2E));
            sv[t] = vi[p * HH + t];
        }
        __syncthreads();
        float c0 = I_LO + (float)i * h;
        float c1 = I_LO + (float)j * h;
        float acc = 0.f;
        #pragma unroll 8
        for (int k = 0; k < HH; ++k) {
            float a = fmaf(c0, sew[k].x, c1 * sew[k].y);
            acc = fmaf(silu_fast(a), sv[k], acc);
        }
        unsigned short ab = f2bf(acc);
        unsigned short* cb = LUTi + (size_t)p * I_CELLS * 4;
        // scatter corner value into the <=4 cells that reference it
        if (i < I_NE - 1 && j < I_NE - 1) cb[((i    ) * I_NE + j    ) * 4 + 0] = ab;
        if (i < I_NE - 1 && j > 0)        cb[((i    ) * I_NE + j - 1) * 4 + 1] = ab;
        if (i > 0        && j < I_NE - 1) cb[((i - 1) * I_NE + j    ) * 4 + 2] = ab;
        if (i > 0        && j > 0)        cb[((i - 1) * I_NE + j - 1) * 4 + 3] = ab;
    }
}

// ---------------- main kernel: 512 rows/block, 1 block/CU, lockstep-p gathers ----
__global__ __launch_bounds__(TPB, 2) void qgam_main(
    const float* __restrict__ X,
    const float* __restrict__ bias_main,
    const float* __restrict__ bias_inter,
    const float* __restrict__ W_final,
    const float* __restrict__ b_final,
    const int* __restrict__ pairs,
    const float* __restrict__ LUTm,
    const ushort4* __restrict__ LUTi,
    float* __restrict__ out,
    float* __restrict__ Zout,
    int nrows)
{
    const float M_INVH = (float)(M_NE - 1) / (M_HI - M_LO);
    const float I_INVH = (float)(I_NE - 1) / (I_HI - I_LO);

    __shared__ float s_lutm[DD * M_NE];    // 16 KB
    __shared__ float s_x[DD][ROWS + 1];    // 65.7 KB
    __shared__ float s_t[DD][ROWS + 1];    // 65.7 KB
    __shared__ float s_wf[DD + PP];
    __shared__ float s_moff[DD];           // -(bm[d]+M_LO)*M_INVH
    __shared__ float s_io0[PP], s_io1[PP];
    __shared__ int   s_p0[PP], s_p1[PP];

    const int tid  = threadIdx.x;
    const int base = blockIdx.x * ROWS;

    // copy main LUT -> LDS (coalesced, L2-resident)
    {
        const float4* __restrict__ lm4 = reinterpret_cast<const float4*>(LUTm);
        float4* __restrict__ sl4 = reinterpret_cast<float4*>(s_lutm);
        #pragma unroll
        for (int k = 0; k < 2; ++k)
            sl4[k * TPB + tid] = lm4[k * TPB + tid];
    }
    // stage X tile coalesced -> LDS transposed (512 rows x 32 cols)
    {
        const float4* __restrict__ Xv =
            reinterpret_cast<const float4*>(X) + (size_t)base * (DD / 4);
        #pragma unroll
        for (int k = 0; k < 8; ++k) {
            const int fi = k * TPB + tid;           // 0..4095 float4 units
            const int rl = fi >> 3;
            const int c  = (fi & 7) * 4;
            if (base + rl < nrows) {
                float4 v = Xv[fi];
                s_x[c + 0][rl] = v.x;
                s_x[c + 1][rl] = v.y;
                s_x[c + 2][rl] = v.z;
                s_x[c + 3][rl] = v.w;
            }
        }
    }
    if (tid < DD + PP) s_wf[tid] = W_final[tid];
    if (tid < PP) {
        s_moff[tid] = -(bias_main[tid] + M_LO) * M_INVH;
        s_io0[tid]  = -(bias_inter[2 * tid + 0] + I_LO) * I_INVH;
        s_io1[tid]  = -(bias_inter[2 * tid + 1] + I_LO) * I_INVH;
        s_p0[tid]   = pairs[2 * tid + 0];
        s_p1[tid]   = pairs[2 * tid + 1];
    }
    __syncthreads();

    const int r = tid;                    // this thread's local row
    const int n = base + r;

    float dot = b_final[0];

    // ---- main part: 32 LDS lerps ----
    #pragma unroll 4
    for (int d = 0; d < DD; ++d) {
        float u  = fmaf(s_x[d][r], M_INVH, s_moff[d]);
        int   ii = (int)floorf(u);
        ii = ii < 0 ? 0 : (ii > M_NE - 2 ? M_NE - 2 : ii);
        float f  = u - (float)ii;
        float t0 = s_lutm[(d << 7) + ii];
        float t1 = s_lutm[(d << 7) + ii + 1];
        float zv = fmaf(f, t1 - t0, t0);
        s_t[d][r] = zv;
        dot = fmaf(zv, s_wf[d], dot);
    }

    // flush round 0: Z cols 0..31 (full-line coalesced float4 stores)
    __syncthreads();
    #pragma unroll
    for (int i = 0; i < 8; ++i) {
        const int fi   = i * TPB + tid;   // 0..4095
        const int rowl = fi >> 3;
        const int c4   = (fi & 7) * 4;
        const int row  = base + rowl;
        if (row < nrows) {
            float4 v = make_float4(s_t[c4 + 0][rowl], s_t[c4 + 1][rowl],
                                   s_t[c4 + 2][rowl], s_t[c4 + 3][rowl]);
            *reinterpret_cast<float4*>(&Zout[(size_t)row * (DD + PP) + c4]) = v;
        }
    }
    __syncthreads();

    // ---- inter part: lockstep p sweep; block's gathers stay in ONE hot region ----
    #pragma unroll 2
    for (int p = 0; p < PP; ++p) {
        const int i0 = s_p0[p], i1 = s_p1[p];
        float u  = fmaf(s_x[i0][r], I_INVH, s_io0[p]);
        float v_ = fmaf(s_x[i1][r], I_INVH, s_io1[p]);
        int   iu = (int)floorf(u);
        int   iv = (int)floorf(v_);
        iu = iu < 0 ? 0 : (iu > I_NE - 2 ? I_NE - 2 : iu);
        iv = iv < 0 ? 0 : (iv > I_NE - 2 ? I_NE - 2 : iv);
        float fu = u  - (float)iu;
        float fv = v_ - (float)iv;
        ushort4 cell = LUTi[(size_t)p * I_CELLS + iu * I_NE + iv];
        float a00 = bf2f(cell.x), a01 = bf2f(cell.y);
        float a10 = bf2f(cell.z), a11 = bf2f(cell.w);
        float r0 = fmaf(fv, a01 - a00, a00);
        float r1 = fmaf(fv, a11 - a10, a10);
        float zv = fmaf(fu, r1 - r0, r0);
        s_t[p][r] = zv;
        dot = fmaf(zv, s_wf[DD + p], dot);
    }

    if (n < nrows) out[n] = dot;

    // flush round 1: Z cols 32..63
    __syncthreads();
    #pragma unroll
    for (int i = 0; i < 8; ++i) {
        const int fi   = i * TPB + tid;
        const int rowl = fi >> 3;
        const int c4   = (fi & 7) * 4;
        const int row  = base + rowl;
        if (row < nrows) {
            float4 v = make_float4(s_t[c4 + 0][rowl], s_t[c4 + 1][rowl],
                                   s_t[c4 + 2][rowl], s_t[c4 + 3][rowl]);
            *reinterpret_cast<float4*>(&Zout[(size_t)row * (DD + PP) + DD + c4]) = v;
        }
    }
}

extern "C" void kernel_launch(void* const* d_in, const int* in_sizes, int n_in,
                              void* d_out, int out_size, void* d_ws, size_t ws_size,
                              hipStream_t stream) {
    const float* X   = (const float*)d_in[0];
    const float* lwm = (const float*)d_in[1];
    const float* bm  = (const float*)d_in[2];
    const float* vm  = (const float*)d_in[3];
    const float* lwi = (const float*)d_in[4];
    const float* bi  = (const float*)d_in[5];
    const float* vi  = (const float*)d_in[6];
    const float* wf  = (const float*)d_in[7];
    const float* bf  = (const float*)d_in[8];
    const int* pairs = (const int*)d_in[9];

    const int nrows = in_sizes[0] / DD;
    float* out = (float*)d_out;          // (N,)
    float* Z   = out + nrows;            // (N, 64)

    float*          LUTm = (float*)d_ws;                 // 32*128*4B = 16 KB
    unsigned short* LUTi = (unsigned short*)((char*)d_ws +
                           ((DD * M_NE * sizeof(float) + 255) & ~255));
                           // 32*9216 cells * 8B = 2.36 MB

    build_luts<<<MAIN_BLOCKS + INTER_BLOCKS, BTPB, 0, stream>>>(lwm, vm, lwi, vi,
                                                                LUTm, LUTi);

    const int grid = (nrows + ROWS - 1) / ROWS;
    qgam_main<<<grid, TPB, 0, stream>>>(X, bm, bi, wf, bf, pairs, LUTm,
                                        (const ushort4*)LUTi, out, Z, nrows);
}